// Round 3
// baseline (2043.578 us; speedup 1.0000x reference)
//
#include <hip/hip_runtime.h>
#include <hip/hip_bf16.h>

typedef __attribute__((ext_vector_type(8))) short bf16x8;
typedef __attribute__((ext_vector_type(4))) float f32x4;
typedef __attribute__((ext_vector_type(4))) short short4v;

static __device__ __forceinline__ short f2bf(float f) {
    __hip_bfloat16 h = __float2bfloat16(f);
    short s; __builtin_memcpy(&s, &h, 2); return s;
}

#define WN_MASK 4095   // windows per batch - 1 (WN=4096, pow2)
#define SEQ 10
#define EDIM 96
#define DHEAD 24
#define N3 288
#define G 4            // windows per group
#define ROWS 40        // G*SEQ
#define XPITCH 104     // 208B rows: 16B-aligned; b128 reads land min-conflict
#define QKP 40         // q/k row pitch (shorts); 80B rows: 16B-aligned, bank stride 20
#define VTP 40
#define PP  40
#define NGROUPS 8
#define WPB 32         // windows per block
#define NBLOCKS 2048   // 2048*32 = 65536 windows; 2 blocks/CU, 4 rounds
#define NTHREADS 512

// LDS layout (bytes); all bf16 payloads are short-typed (uniform TBAA class)
// Total 75200 B -> 2 blocks/CU (150400 <= 163840)
#define XO_OFF    0
#define XO_BYTES  (ROWS*XPITCH*2)          // 8320  (X tile, reused as attn_out)
#define Q_OFF     (XO_OFF + XO_BYTES)      // 8320
#define Q_BYTES   (G*4*SEQ*QKP*2)          // 12800 (10 real rows/pair; rows 10..15
#define K_OFF     (Q_OFF + Q_BYTES)        // 21120  overflow-read into next region,
#define VT_OFF    (K_OFF + Q_BYTES)        // 33920  values masked downstream)
#define VT_BYTES  (G*4*DHEAD*VTP*2)        // 30720 (24 d-rows; t=1 reads overflow, discarded)
#define P_OFF     (VT_OFF + VT_BYTES)      // 64640
#define P_BYTES   (8*16*PP*2)              // 10240
#define POS_OFF   (P_OFF + P_BYTES)        // 74880
#define POS_BYTES (320)
#define SMEM_BYTES (POS_OFF + POS_BYTES)   // 75200

__global__ __launch_bounds__(NTHREADS, 4)
void swin_msa_fused(const float* __restrict__ X,
                    const float* __restrict__ Wqkv,
                    const float* __restrict__ bqkv,
                    const float* __restrict__ Wo,
                    const float* __restrict__ bo,
                    const float* __restrict__ pos,
                    float* __restrict__ out)
{
    extern __shared__ char smem[];
    short* xo = (short*)(smem + XO_OFF);
    short* qs = (short*)(smem + Q_OFF);
    short* ks = (short*)(smem + K_OFF);
    short* vt = (short*)(smem + VT_OFF);
    short* pb = (short*)(smem + P_OFF);
    float* posf = (float*)(smem + POS_OFF);

    const int tid  = threadIdx.x;
    const int wave = tid >> 6;
    const int lane = tid & 63;
    const int l15  = lane & 15;
    const int quad = lane >> 4;
    const int k0   = quad * 8;
    const int wb0  = blockIdx.x * WPB;

    // one-time zero of q/k/vT/p buffers (covers all zero-padding regions;
    // live regions are rewritten every group, pad regions never written again)
    {
        uint4* z = (uint4*)(smem + Q_OFF);
        const int n16 = (POS_OFF - Q_OFF) / 16;
        for (int i = tid; i < n16; i += NTHREADS) z[i] = make_uint4(0u,0u,0u,0u);
    }
    for (int i = tid; i < 76; i += NTHREADS) posf[i] = pos[i];
    __syncthreads();

    // Weight pointers held in SGPRs; redefined each group iteration via empty
    // asm so weight loads are formally loop-variant: blocks LICM/CSE from
    // recreating live-across-loop fragment registers (the spill source).
    const float* wq = Wqkv;
    const float* wo = Wo;
    const float* bq = bqkv;
    const float* bb = bo;

    const float scale = 0.20412414523193154f;  // 24^-0.5
#pragma clang loop unroll(disable)
    for (int g = 0; g < NGROUPS; ++g) {
      asm volatile("" : "+s"(wq), "+s"(wo), "+s"(bq), "+s"(bb));
      const int wbase = wb0 + g*G;
      const long rowbase = (long)wbase * SEQ;

      // ---- stage X: 40 rows x 96 fp32 -> bf16 LDS, pitch 104 ----
      {
        const float4* src = (const float4*)(X + rowbase * (long)EDIM);
        for (int c = tid; c < ROWS*24; c += NTHREADS) {
          float4 v = src[c];
          const int r = c / 24, cc = c - r*24;
          short4v s4 = { f2bf(v.x), f2bf(v.y), f2bf(v.z), f2bf(v.w) };
          *(short4v*)&xo[r*XPITCH + cc*4] = s4;
        }
      }

      // ---- rebuild W_qkv B-fragments from L2 (loads overlap stage/barrier);
      // wave w owns n-tiles {w, w+8, w+16} of 18 -> <=9 fragments, 36 VGPR,
      // live only within this group iteration ----
      bf16x8 bw[3][3];   // [ti][k-step]
      float biasq[3] = {0.f, 0.f, 0.f};
#pragma unroll
      for (int ti = 0; ti < 3; ++ti) {
        const int n = ti*8 + wave;       // wave-uniform
        if (n < 18) {
          const int gc = n*16 + l15;     // global col in [0,288)
          biasq[ti] = bq[gc];
#pragma unroll
          for (int kk = 0; kk < 3; ++kk) {
            bf16x8 f;
#pragma unroll
            for (int jj = 0; jj < 8; ++jj)
              f[jj] = f2bf(wq[(kk*32 + k0 + jj)*N3 + gc]);
            bw[ti][kk] = f;
          }
        }
      }
      __syncthreads();

      // ---- QKV projection: m-tiles 0..2, per wave its owned n-tiles ----
      for (int m = 0; m < 3; ++m) {
        // m==2 reads rows 40..47 beyond xo: garbage -> output rows discarded
        const bf16x8 a0 = *(const bf16x8*)&xo[(m*16 + l15)*XPITCH +  0 + k0];
        const bf16x8 a1 = *(const bf16x8*)&xo[(m*16 + l15)*XPITCH + 32 + k0];
        const bf16x8 a2 = *(const bf16x8*)&xo[(m*16 + l15)*XPITCH + 64 + k0];
#pragma unroll
        for (int ti = 0; ti < 3; ++ti) {
          const int n = ti*8 + wave;     // wave-uniform predicate
          if (n < 18) {
            f32x4 acc = {0.f,0.f,0.f,0.f};
            acc = __builtin_amdgcn_mfma_f32_16x16x32_bf16(a0, bw[ti][0], acc, 0,0,0);
            acc = __builtin_amdgcn_mfma_f32_16x16x32_bf16(a1, bw[ti][1], acc, 0,0,0);
            acc = __builtin_amdgcn_mfma_f32_16x16x32_bf16(a2, bw[ti][2], acc, 0,0,0);
            const int gc = n*16 + l15;
            const int p  = n / 6;        // part boundaries align with n-tiles
            const int pc = gc - p*96;
            const int head = pc / 24;    // per-lane (may differ within fragment)
            const int d    = pc - head*24;
            const float bias = biasq[ti];
#pragma unroll
            for (int r = 0; r < 4; ++r) {
              const int R = m*16 + quad*4 + r;
              if (R < ROWS) {            // m==2 tail rows discarded
                const int w = R / 10, s = R - w*10;
                float v = acc[r] + bias;
                if (p == 0) {
                  v *= scale;
                  qs[((w*4 + head)*SEQ + s)*QKP + d] = f2bf(v);
                } else if (p == 1) {
                  ks[((w*4 + head)*SEQ + s)*QKP + d] = f2bf(v);
                } else {
                  vt[((w*4 + head)*DHEAD + d)*VTP + s] = f2bf(v);
                }
              }
            }
          }
        }
      }
      __syncthreads();

      // ---- rebuild W_o B-fragments (waves 0..5); loads hide under attention ----
      bf16x8 bwo[3];
      float bo_val = 0.f;
      if (wave < 6) {
        const int col = wave*16 + l15;
        bo_val = bb[col];
#pragma unroll
        for (int kk = 0; kk < 3; ++kk) {
          bf16x8 f;
#pragma unroll
          for (int jj = 0; jj < 8; ++jj)
            f[jj] = f2bf(wo[(kk*32 + k0 + jj)*EDIM + col]);
          bwo[kk] = f;
        }
      }

      // ---- attention: 16 (window,head) pairs, 2 per wave ----
#pragma unroll
      for (int ii = 0; ii < 2; ++ii) {
        const int pair = wave*2 + ii;
        const int w = pair >> 2, hh = pair & 3;
        const short* qbase = qs + (w*4 + hh)*SEQ*QKP;
        const short* kbase = ks + (w*4 + hh)*SEQ*QKP;
        // rows l15 >= 10 overflow-read the next pair's region: garbage, but
        // output rows i>=10 are discarded and key cols j>=10 are re-masked.
        const bf16x8 qf = *(const bf16x8*)&qbase[l15*QKP + k0];
        const bf16x8 kf = *(const bf16x8*)&kbase[l15*QKP + k0];
        f32x4 sacc = {0.f,0.f,0.f,0.f};
        sacc = __builtin_amdgcn_mfma_f32_16x16x32_bf16(qf, kf, sacc, 0,0,0);
        // shift mask applies to the last window of EACH batch (wn == WN-1)
        const bool islast = ((wbase + w) & WN_MASK) == WN_MASK;
        const int j = l15;
        float pr[4];
#pragma unroll
        for (int r = 0; r < 4; ++r) {
          const int i = quad*4 + r;
          int idx = j - i + 9;
          idx = idx < 0 ? 0 : (idx > 18 ? 18 : idx);
          float sv = sacc[r] + posf[idx*4 + hh];
          if (islast && ((i < 5) != (j < 5))) sv -= 100.f;
          if (j >= 10) sv = -1e30f;           // overwrite: kills overflow garbage/NaN
          float mx = sv;
          mx = fmaxf(mx, __shfl_xor(mx, 1, 16));
          mx = fmaxf(mx, __shfl_xor(mx, 2, 16));
          mx = fmaxf(mx, __shfl_xor(mx, 4, 16));
          mx = fmaxf(mx, __shfl_xor(mx, 8, 16));
          float e = __expf(sv - mx);
          float sm = e;
          sm += __shfl_xor(sm, 1, 16);
          sm += __shfl_xor(sm, 2, 16);
          sm += __shfl_xor(sm, 4, 16);
          sm += __shfl_xor(sm, 8, 16);
          pr[r] = e / sm;
        }
        short* pbw = pb + wave*16*PP;
#pragma unroll
        for (int r = 0; r < 4; ++r)
          pbw[(quad*4 + r)*PP + j] = f2bf(pr[r]);
        // C-layout -> A-layout round trip. Intra-wave: DS pipe is in-order per
        // wave; fences stop compiler reordering of may-alias LDS accesses.
        asm volatile("" ::: "memory");
        const bf16x8 pf = *(const bf16x8*)&pbw[l15*PP + k0];
        asm volatile("" ::: "memory");
        const short* vbase = vt + (w*4 + hh)*DHEAD*VTP;
#pragma unroll
        for (int t = 0; t < 2; ++t) {
          const bf16x8 vf = *(const bf16x8*)&vbase[(t*16 + l15)*VTP + k0];
          f32x4 oacc = {0.f,0.f,0.f,0.f};
          oacc = __builtin_amdgcn_mfma_f32_16x16x32_bf16(pf, vf, oacc, 0,0,0);
          const int d = t*16 + l15;
          if (d < DHEAD) {
#pragma unroll
            for (int r = 0; r < 4; ++r) {
              const int i = quad*4 + r;
              if (i < 10)
                xo[(w*10 + i)*XPITCH + hh*DHEAD + d] = f2bf(oacc[r]);
            }
          }
        }
      }
      __syncthreads();

      // ---- output projection: wave = N-tile (waves 0..5) ----
      if (wave < 6) {
        for (int m = 0; m < 3; ++m) {
          const bf16x8 a0 = *(const bf16x8*)&xo[(m*16 + l15)*XPITCH +  0 + k0];
          const bf16x8 a1 = *(const bf16x8*)&xo[(m*16 + l15)*XPITCH + 32 + k0];
          const bf16x8 a2 = *(const bf16x8*)&xo[(m*16 + l15)*XPITCH + 64 + k0];
          f32x4 acc = {0.f,0.f,0.f,0.f};
          acc = __builtin_amdgcn_mfma_f32_16x16x32_bf16(a0, bwo[0], acc, 0,0,0);
          acc = __builtin_amdgcn_mfma_f32_16x16x32_bf16(a1, bwo[1], acc, 0,0,0);
          acc = __builtin_amdgcn_mfma_f32_16x16x32_bf16(a2, bwo[2], acc, 0,0,0);
          const int col = wave*16 + l15;
#pragma unroll
          for (int r = 0; r < 4; ++r) {
            const int R = m*16 + quad*4 + r;
            if (R < ROWS)
              out[(rowbase + R)*EDIM + col] = acc[r] + bo_val;
          }
        }
      }
      __syncthreads();
    }
}

extern "C" void kernel_launch(void* const* d_in, const int* in_sizes, int n_in,
                              void* d_out, int out_size, void* d_ws, size_t ws_size,
                              hipStream_t stream) {
    const float* X    = (const float*)d_in[0];
    const float* Wqkv = (const float*)d_in[1];
    const float* bqkv = (const float*)d_in[2];
    const float* Wo   = (const float*)d_in[3];
    const float* bo   = (const float*)d_in[4];
    const float* pos  = (const float*)d_in[5];
    float* out = (float*)d_out;

    (void)hipFuncSetAttribute((const void*)swin_msa_fused,
                              hipFuncAttributeMaxDynamicSharedMemorySize,
                              SMEM_BYTES);
    swin_msa_fused<<<dim3(NBLOCKS), dim3(NTHREADS), SMEM_BYTES, stream>>>(
        X, Wqkv, bqkv, Wo, bo, pos, out);
}

// Round 4
// 709.994 us; speedup vs baseline: 2.8783x; 2.8783x over previous
//
#include <hip/hip_runtime.h>
#include <hip/hip_bf16.h>

typedef __attribute__((ext_vector_type(8))) short bf16x8;
typedef __attribute__((ext_vector_type(4))) float f32x4;
typedef __attribute__((ext_vector_type(4))) short short4v;

static __device__ __forceinline__ short f2bf(float f) {
    __hip_bfloat16 h = __float2bfloat16(f);
    short s; __builtin_memcpy(&s, &h, 2); return s;
}

#define WN_MASK 4095   // windows per batch - 1 (WN=4096, pow2)
#define SEQ 10
#define EDIM 96
#define DHEAD 24
#define N3 288
#define G 4            // windows per group
#define ROWS 40        // G*SEQ
#define XPITCH 104     // 208B rows: 16B-aligned
#define QKP 40         // q/k row pitch (shorts); 80B rows: 16B-aligned, bank stride 20
#define VTP 40
#define PP  40
#define NGROUPS 8
#define WPB 32         // windows per block
#define NBLOCKS 2048   // 2048*32 = 65536 windows; 2 blocks/CU resident
#define NTHREADS 512

// LDS layout (bytes); all bf16 payloads are short-typed (uniform TBAA class)
// Total 75200 B -> 2 blocks/CU (150400 <= 163840)
#define XO_OFF    0
#define XO_BYTES  (ROWS*XPITCH*2)          // 8320  (X tile, reused as attn_out)
#define Q_OFF     (XO_OFF + XO_BYTES)      // 8320
#define Q_BYTES   (G*4*SEQ*QKP*2)          // 12800 (10 real rows/pair; rows 10..15
#define K_OFF     (Q_OFF + Q_BYTES)        // 21120  overflow-read into next region,
#define VT_OFF    (K_OFF + Q_BYTES)        // 33920  values masked downstream)
#define VT_BYTES  (G*4*DHEAD*VTP*2)        // 30720 (24 d-rows; t=1 reads overflow, discarded)
#define P_OFF     (VT_OFF + VT_BYTES)      // 64640
#define P_BYTES   (8*16*PP*2)              // 10240
#define POS_OFF   (P_OFF + P_BYTES)        // 74880
#define POS_BYTES (320)
#define SMEM_BYTES (POS_OFF + POS_BYTES)   // 75200

// __launch_bounds__ 2nd arg: empirically (512,4) capped the allocator at 64
// VGPRs (8 waves/SIMD budget) -> massive scratch spill of persistent weight
// fragments. (512,2) = 2 blocks/CU = 16 waves/CU = 128-reg budget; body needs
// ~105. LDS (75.2KB*2 <= 160KB) gives the same 2 blocks/CU.
__global__ __launch_bounds__(NTHREADS, 2)
void swin_msa_fused(const float* __restrict__ X,
                    const float* __restrict__ Wqkv,
                    const float* __restrict__ bqkv,
                    const float* __restrict__ Wo,
                    const float* __restrict__ bo,
                    const float* __restrict__ pos,
                    float* __restrict__ out)
{
    extern __shared__ char smem[];
    short* xo = (short*)(smem + XO_OFF);
    short* qs = (short*)(smem + Q_OFF);
    short* ks = (short*)(smem + K_OFF);
    short* vt = (short*)(smem + VT_OFF);
    short* pb = (short*)(smem + P_OFF);
    float* posf = (float*)(smem + POS_OFF);

    const int tid  = threadIdx.x;
    const int wave = tid >> 6;
    const int lane = tid & 63;
    const int l15  = lane & 15;
    const int quad = lane >> 4;
    const int k0   = quad * 8;
    const int wb0  = blockIdx.x * WPB;

    // one-time zero of q/k/vT/p buffers (covers all zero-padding regions;
    // live regions are rewritten every group, pad regions never written again)
    {
        uint4* z = (uint4*)(smem + Q_OFF);
        const int n16 = (POS_OFF - Q_OFF) / 16;
        for (int i = tid; i < n16; i += NTHREADS) z[i] = make_uint4(0u,0u,0u,0u);
    }
    for (int i = tid; i < 76; i += NTHREADS) posf[i] = pos[i];

    // persistent W_qkv B-fragments: full 288-col output tiled as 18 n-tiles of 16;
    // wave w owns n-tiles {w, w+8, w+16} -> <=9 fragments (36 VGPR), no zero halves
    bf16x8 bw[3][3];   // [ti][k-step]
    float biasq[3];
#pragma unroll
    for (int ti = 0; ti < 3; ++ti) {
      const int n = ti*8 + wave;
      if (n < 18) {
        const int gc = n*16 + l15;             // global col in [0,288)
        biasq[ti] = bqkv[gc];
#pragma unroll
        for (int kk = 0; kk < 3; ++kk) {
          bf16x8 f;
#pragma unroll
          for (int jj = 0; jj < 8; ++jj)
            f[jj] = f2bf(Wqkv[(kk*32 + k0 + jj)*N3 + gc]);
          bw[ti][kk] = f;
        }
      } else {
        biasq[ti] = 0.f;
#pragma unroll
        for (int kk = 0; kk < 3; ++kk) {
          bf16x8 f;
#pragma unroll
          for (int jj = 0; jj < 8; ++jj) f[jj] = (short)0;
          bw[ti][kk] = f;
        }
      }
    }
    // persistent W_o B-fragments: wave = N-tile (waves 0..5)
    bf16x8 bwo[3];
    float bo_val = 0.f;
    if (wave < 6) {
      const int col = wave*16 + l15;
      bo_val = bo[col];
#pragma unroll
      for (int kk = 0; kk < 3; ++kk) {
        bf16x8 f;
#pragma unroll
        for (int jj = 0; jj < 8; ++jj) {
          const int krow = kk*32 + k0 + jj;
          f[jj] = f2bf(Wo[krow*EDIM + col]);
        }
        bwo[kk] = f;
      }
    }
    __syncthreads();

    const float scale = 0.20412414523193154f;  // 24^-0.5
#pragma clang loop unroll(disable)
    for (int g = 0; g < NGROUPS; ++g) {
      const int wbase = wb0 + g*G;
      const long rowbase = (long)wbase * SEQ;

      // ---- stage X: 40 rows x 96 fp32 -> bf16 LDS, pitch 104 ----
      {
        const float4* src = (const float4*)(X + rowbase * (long)EDIM);
        for (int c = tid; c < ROWS*24; c += NTHREADS) {
          float4 v = src[c];
          const int r = c / 24, cc = c - r*24;
          short4v s4 = { f2bf(v.x), f2bf(v.y), f2bf(v.z), f2bf(v.w) };
          *(short4v*)&xo[r*XPITCH + cc*4] = s4;
        }
      }
      __syncthreads();

      // ---- QKV projection: m-tiles 0..2, per wave its owned n-tiles ----
      for (int m = 0; m < 3; ++m) {
        // m==2 reads rows 40..47 beyond xo: garbage -> output rows discarded
        const bf16x8 a0 = *(const bf16x8*)&xo[(m*16 + l15)*XPITCH +  0 + k0];
        const bf16x8 a1 = *(const bf16x8*)&xo[(m*16 + l15)*XPITCH + 32 + k0];
        const bf16x8 a2 = *(const bf16x8*)&xo[(m*16 + l15)*XPITCH + 64 + k0];
#pragma unroll
        for (int ti = 0; ti < 3; ++ti) {
          const int n = ti*8 + wave;     // wave-uniform predicate
          if (n < 18) {
            f32x4 acc = {0.f,0.f,0.f,0.f};
            acc = __builtin_amdgcn_mfma_f32_16x16x32_bf16(a0, bw[ti][0], acc, 0,0,0);
            acc = __builtin_amdgcn_mfma_f32_16x16x32_bf16(a1, bw[ti][1], acc, 0,0,0);
            acc = __builtin_amdgcn_mfma_f32_16x16x32_bf16(a2, bw[ti][2], acc, 0,0,0);
            const int gc = n*16 + l15;
            const int p  = n / 6;        // part boundaries align with n-tiles
            const int pc = gc - p*96;
            const int head = pc / 24;    // per-lane (may differ within fragment)
            const int d    = pc - head*24;
            const float bias = biasq[ti];
#pragma unroll
            for (int r = 0; r < 4; ++r) {
              const int R = m*16 + quad*4 + r;
              if (R < ROWS) {            // m==2 tail rows discarded
                const int w = R / 10, s = R - w*10;
                float v = acc[r] + bias;
                if (p == 0) {
                  v *= scale;
                  qs[((w*4 + head)*SEQ + s)*QKP + d] = f2bf(v);
                } else if (p == 1) {
                  ks[((w*4 + head)*SEQ + s)*QKP + d] = f2bf(v);
                } else {
                  vt[((w*4 + head)*DHEAD + d)*VTP + s] = f2bf(v);
                }
              }
            }
          }
        }
      }
      __syncthreads();

      // ---- attention: 16 (window,head) pairs, 2 per wave ----
#pragma unroll
      for (int ii = 0; ii < 2; ++ii) {
        const int pair = wave*2 + ii;
        const int w = pair >> 2, hh = pair & 3;
        const short* qbase = qs + (w*4 + hh)*SEQ*QKP;
        const short* kbase = ks + (w*4 + hh)*SEQ*QKP;
        // rows l15 >= 10 overflow-read the next pair's region: garbage, but
        // output rows i>=10 are discarded and key cols j>=10 are re-masked.
        const bf16x8 qf = *(const bf16x8*)&qbase[l15*QKP + k0];
        const bf16x8 kf = *(const bf16x8*)&kbase[l15*QKP + k0];
        f32x4 sacc = {0.f,0.f,0.f,0.f};
        sacc = __builtin_amdgcn_mfma_f32_16x16x32_bf16(qf, kf, sacc, 0,0,0);
        // shift mask applies to the last window of EACH batch (wn == WN-1)
        const bool islast = ((wbase + w) & WN_MASK) == WN_MASK;
        const int j = l15;
        float pr[4];
#pragma unroll
        for (int r = 0; r < 4; ++r) {
          const int i = quad*4 + r;
          int idx = j - i + 9;
          idx = idx < 0 ? 0 : (idx > 18 ? 18 : idx);
          float sv = sacc[r] + posf[idx*4 + hh];
          if (islast && ((i < 5) != (j < 5))) sv -= 100.f;
          if (j >= 10) sv = -1e30f;           // overwrite: kills overflow garbage/NaN
          float mx = sv;
          mx = fmaxf(mx, __shfl_xor(mx, 1, 16));
          mx = fmaxf(mx, __shfl_xor(mx, 2, 16));
          mx = fmaxf(mx, __shfl_xor(mx, 4, 16));
          mx = fmaxf(mx, __shfl_xor(mx, 8, 16));
          float e = __expf(sv - mx);
          float sm = e;
          sm += __shfl_xor(sm, 1, 16);
          sm += __shfl_xor(sm, 2, 16);
          sm += __shfl_xor(sm, 4, 16);
          sm += __shfl_xor(sm, 8, 16);
          pr[r] = e / sm;
        }
        short* pbw = pb + wave*16*PP;
#pragma unroll
        for (int r = 0; r < 4; ++r)
          pbw[(quad*4 + r)*PP + j] = f2bf(pr[r]);
        // C-layout -> A-layout round trip. Intra-wave: DS pipe is in-order per
        // wave; fences stop compiler reordering of may-alias LDS accesses.
        asm volatile("" ::: "memory");
        const bf16x8 pf = *(const bf16x8*)&pbw[l15*PP + k0];
        asm volatile("" ::: "memory");
        const short* vbase = vt + (w*4 + hh)*DHEAD*VTP;
#pragma unroll
        for (int t = 0; t < 2; ++t) {
          const bf16x8 vf = *(const bf16x8*)&vbase[(t*16 + l15)*VTP + k0];
          f32x4 oacc = {0.f,0.f,0.f,0.f};
          oacc = __builtin_amdgcn_mfma_f32_16x16x32_bf16(pf, vf, oacc, 0,0,0);
          const int d = t*16 + l15;
          if (d < DHEAD) {
#pragma unroll
            for (int r = 0; r < 4; ++r) {
              const int i = quad*4 + r;
              if (i < 10)
                xo[(w*10 + i)*XPITCH + hh*DHEAD + d] = f2bf(oacc[r]);
            }
          }
        }
      }
      __syncthreads();

      // ---- output projection: wave = N-tile (waves 0..5) ----
      if (wave < 6) {
        for (int m = 0; m < 3; ++m) {
          const bf16x8 a0 = *(const bf16x8*)&xo[(m*16 + l15)*XPITCH +  0 + k0];
          const bf16x8 a1 = *(const bf16x8*)&xo[(m*16 + l15)*XPITCH + 32 + k0];
          const bf16x8 a2 = *(const bf16x8*)&xo[(m*16 + l15)*XPITCH + 64 + k0];
          f32x4 acc = {0.f,0.f,0.f,0.f};
          acc = __builtin_amdgcn_mfma_f32_16x16x32_bf16(a0, bwo[0], acc, 0,0,0);
          acc = __builtin_amdgcn_mfma_f32_16x16x32_bf16(a1, bwo[1], acc, 0,0,0);
          acc = __builtin_amdgcn_mfma_f32_16x16x32_bf16(a2, bwo[2], acc, 0,0,0);
          const int col = wave*16 + l15;
#pragma unroll
          for (int r = 0; r < 4; ++r) {
            const int R = m*16 + quad*4 + r;
            if (R < ROWS)
              out[(rowbase + R)*EDIM + col] = acc[r] + bo_val;
          }
        }
      }
      __syncthreads();
    }
}

extern "C" void kernel_launch(void* const* d_in, const int* in_sizes, int n_in,
                              void* d_out, int out_size, void* d_ws, size_t ws_size,
                              hipStream_t stream) {
    const float* X    = (const float*)d_in[0];
    const float* Wqkv = (const float*)d_in[1];
    const float* bqkv = (const float*)d_in[2];
    const float* Wo   = (const float*)d_in[3];
    const float* bo   = (const float*)d_in[4];
    const float* pos  = (const float*)d_in[5];
    float* out = (float*)d_out;

    (void)hipFuncSetAttribute((const void*)swin_msa_fused,
                              hipFuncAttributeMaxDynamicSharedMemorySize,
                              SMEM_BYTES);
    swin_msa_fused<<<dim3(NBLOCKS), dim3(NTHREADS), SMEM_BYTES, stream>>>(
        X, Wqkv, bqkv, Wo, bo, pos, out);
}

// Round 5
// 655.905 us; speedup vs baseline: 3.1157x; 1.0825x over previous
//
#include <hip/hip_runtime.h>
#include <hip/hip_bf16.h>

typedef __attribute__((ext_vector_type(8))) short bf16x8;
typedef __attribute__((ext_vector_type(4))) float f32x4;
typedef __attribute__((ext_vector_type(4))) short short4v;

static __device__ __forceinline__ short f2bf(float f) {
    __hip_bfloat16 h = __float2bfloat16(f);
    short s; __builtin_memcpy(&s, &h, 2); return s;
}
static __device__ __forceinline__ unsigned pk2(float a, float b) {
    unsigned u = (unsigned)(unsigned short)f2bf(a);
    u |= ((unsigned)(unsigned short)f2bf(b)) << 16;
    return u;
}

#define WN_MASK 4095   // windows per batch - 1 (WN=4096, pow2)
#define SEQ 10
#define EDIM 96
#define DHEAD 24
#define N3 288
#define G 4            // windows per group
#define ROWS 40        // G*SEQ
#define XPITCH 104     // 208B rows: 16B-aligned
#define QKP 40         // q/k row pitch (shorts); 80B rows: 16B-aligned, bank stride 20
#define VTP 40
#define NGROUPS 8
#define WPB 32         // windows per block
#define NBLOCKS 2048   // 2048*32 = 65536 windows
#define NTHREADS 512

// LDS layout (bytes); all bf16 payloads are short-typed (uniform TBAA class)
// Total 64,960 B: fits 2 blocks/CU even under a 64KB LDS allocation granule
// (P buffer eliminated via shfl-based transpose of swapped-QK^T output).
#define XO_OFF    0
#define XO_BYTES  (ROWS*XPITCH*2)          // 8320  (X tile, reused as attn_out)
#define Q_OFF     (XO_OFF + XO_BYTES)      // 8320
#define Q_BYTES   (G*4*SEQ*QKP*2)          // 12800 (10 real rows/pair; rows 10..15
#define K_OFF     (Q_OFF + Q_BYTES)        // 21120  overflow-read into next region,
#define VT_OFF    (K_OFF + Q_BYTES)        // 33920  values masked downstream)
#define VT_BYTES  (G*4*DHEAD*VTP*2)        // 30720 (24 d-rows; t=1 reads overflow, discarded)
#define POS_OFF   (VT_OFF + VT_BYTES)      // 64640
#define POS_BYTES (320)
#define SMEM_BYTES (POS_OFF + POS_BYTES)   // 64960

// 2nd arg is min BLOCKS/CU (CUDA semantics): (512,2) -> 4 waves/EU -> 128-reg
// cap; body fits at ~92-110 with no spill (R4: WRITE_SIZE exactly = output).
__global__ __launch_bounds__(NTHREADS, 2)
void swin_msa_fused(const float* __restrict__ X,
                    const float* __restrict__ Wqkv,
                    const float* __restrict__ bqkv,
                    const float* __restrict__ Wo,
                    const float* __restrict__ bo,
                    const float* __restrict__ pos,
                    float* __restrict__ out)
{
    extern __shared__ char smem[];
    short* xo = (short*)(smem + XO_OFF);
    short* qs = (short*)(smem + Q_OFF);
    short* ks = (short*)(smem + K_OFF);
    short* vt = (short*)(smem + VT_OFF);
    float* posf = (float*)(smem + POS_OFF);

    const int tid  = threadIdx.x;
    const int wave = tid >> 6;
    const int lane = tid & 63;
    const int l15  = lane & 15;
    const int quad = lane >> 4;
    const int k0   = quad * 8;
    const int wb0  = blockIdx.x * WPB;

    // one-time zero of q/k/vT buffers (covers all zero-padding regions;
    // live regions are rewritten every group, pad regions never written again)
    {
        uint4* z = (uint4*)(smem + Q_OFF);
        const int n16 = (POS_OFF - Q_OFF) / 16;
        for (int i = tid; i < n16; i += NTHREADS) z[i] = make_uint4(0u,0u,0u,0u);
    }
    for (int i = tid; i < 76; i += NTHREADS) posf[i] = pos[i];

    // persistent W_qkv B-fragments: full 288-col output tiled as 18 n-tiles of 16;
    // wave w owns n-tiles {w, w+8, w+16} -> <=9 fragments (36 VGPR), no zero halves
    bf16x8 bw[3][3];   // [ti][k-step]
    float biasq[3];
#pragma unroll
    for (int ti = 0; ti < 3; ++ti) {
      const int n = ti*8 + wave;
      if (n < 18) {
        const int gc = n*16 + l15;             // global col in [0,288)
        biasq[ti] = bqkv[gc];
#pragma unroll
        for (int kk = 0; kk < 3; ++kk) {
          bf16x8 f;
#pragma unroll
          for (int jj = 0; jj < 8; ++jj)
            f[jj] = f2bf(Wqkv[(kk*32 + k0 + jj)*N3 + gc]);
          bw[ti][kk] = f;
        }
      } else {
        biasq[ti] = 0.f;
#pragma unroll
        for (int kk = 0; kk < 3; ++kk) {
          bf16x8 f;
#pragma unroll
          for (int jj = 0; jj < 8; ++jj) f[jj] = (short)0;
          bw[ti][kk] = f;
        }
      }
    }
    // persistent W_o B-fragments: wave = N-tile (waves 0..5)
    bf16x8 bwo[3];
    float bo_val = 0.f;
    if (wave < 6) {
      const int col = wave*16 + l15;
      bo_val = bo[col];
#pragma unroll
      for (int kk = 0; kk < 3; ++kk) {
        bf16x8 f;
#pragma unroll
        for (int jj = 0; jj < 8; ++jj) {
          const int krow = kk*32 + k0 + jj;
          f[jj] = f2bf(Wo[krow*EDIM + col]);
        }
        bwo[kk] = f;
      }
    }
    __syncthreads();

    const float scale = 0.20412414523193154f;  // 24^-0.5
#pragma clang loop unroll(disable)
    for (int g = 0; g < NGROUPS; ++g) {
      const int wbase = wb0 + g*G;
      const long rowbase = (long)wbase * SEQ;

      // ---- stage X: 40 rows x 96 fp32 -> bf16 LDS, pitch 104 ----
      {
        const float4* src = (const float4*)(X + rowbase * (long)EDIM);
        for (int c = tid; c < ROWS*24; c += NTHREADS) {
          float4 v = src[c];
          const int r = c / 24, cc = c - r*24;
          short4v s4 = { f2bf(v.x), f2bf(v.y), f2bf(v.z), f2bf(v.w) };
          *(short4v*)&xo[r*XPITCH + cc*4] = s4;
        }
      }
      __syncthreads();

      // ---- QKV projection: m-tiles 0..2, per wave its owned n-tiles ----
      for (int m = 0; m < 3; ++m) {
        // m==2 reads rows 40..47 beyond xo: garbage -> output rows discarded
        const bf16x8 a0 = *(const bf16x8*)&xo[(m*16 + l15)*XPITCH +  0 + k0];
        const bf16x8 a1 = *(const bf16x8*)&xo[(m*16 + l15)*XPITCH + 32 + k0];
        const bf16x8 a2 = *(const bf16x8*)&xo[(m*16 + l15)*XPITCH + 64 + k0];
#pragma unroll
        for (int ti = 0; ti < 3; ++ti) {
          const int n = ti*8 + wave;     // wave-uniform predicate
          if (n < 18) {
            f32x4 acc = {0.f,0.f,0.f,0.f};
            acc = __builtin_amdgcn_mfma_f32_16x16x32_bf16(a0, bw[ti][0], acc, 0,0,0);
            acc = __builtin_amdgcn_mfma_f32_16x16x32_bf16(a1, bw[ti][1], acc, 0,0,0);
            acc = __builtin_amdgcn_mfma_f32_16x16x32_bf16(a2, bw[ti][2], acc, 0,0,0);
            const int gc = n*16 + l15;
            const int p  = n / 6;        // part boundaries align with n-tiles
            const int pc = gc - p*96;
            const int head = pc / 24;    // per-lane (may differ within fragment)
            const int d    = pc - head*24;
            const float bias = biasq[ti];
#pragma unroll
            for (int r = 0; r < 4; ++r) {
              const int R = m*16 + quad*4 + r;
              if (R < ROWS) {            // m==2 tail rows discarded
                const int w = R / 10, s = R - w*10;
                float v = acc[r] + bias;
                if (p == 0) {
                  v *= scale;
                  qs[((w*4 + head)*SEQ + s)*QKP + d] = f2bf(v);
                } else if (p == 1) {
                  ks[((w*4 + head)*SEQ + s)*QKP + d] = f2bf(v);
                } else {
                  vt[((w*4 + head)*DHEAD + d)*VTP + s] = f2bf(v);
                }
              }
            }
          }
        }
      }
      __syncthreads();

      // ---- attention: 16 (window,head) pairs, 2 per wave ----
#pragma unroll
      for (int ii = 0; ii < 2; ++ii) {
        const int pair = wave*2 + ii;
        const int w = pair >> 2, hh = pair & 3;
        const short* qbase = qs + (w*4 + hh)*SEQ*QKP;
        const short* kbase = ks + (w*4 + hh)*SEQ*QKP;
        // rows l15 >= 10 overflow-read the next pair's region: garbage, but
        // key rows k>=10 are re-masked and query rows i>=10 are discarded.
        const bf16x8 qf = *(const bf16x8*)&qbase[l15*QKP + k0];
        const bf16x8 kf = *(const bf16x8*)&kbase[l15*QKP + k0];
        // SWAPPED operands: D = K*Q^T = S^T. Lane(quad,l15) reg r holds
        // S[i=l15][k=quad*4+r]: softmax axis k = 3 in-lane ops + 2 shfl;
        // garbage rows (l15>=10) never mix into valid rows' reductions.
        f32x4 sacc = {0.f,0.f,0.f,0.f};
        sacc = __builtin_amdgcn_mfma_f32_16x16x32_bf16(kf, qf, sacc, 0,0,0);
        // shift mask applies to the last window of EACH batch (wn == WN-1)
        const bool islast = ((wbase + w) & WN_MASK) == WN_MASK;
        const int i = l15;                  // query row
        float sv[4];
        float mx = -1e30f;
#pragma unroll
        for (int r = 0; r < 4; ++r) {
          const int k = quad*4 + r;         // key index
          int idx = k - i + 9;
          idx = idx < 0 ? 0 : (idx > 18 ? 18 : idx);
          float s = sacc[r] + posf[idx*4 + hh];
          if (islast && ((i < 5) != (k < 5))) s -= 100.f;
          if (k >= 10) s = -1e30f;          // overwrite: kills overflow garbage/NaN
          sv[r] = s;
          mx = fmaxf(mx, s);
        }
        mx = fmaxf(mx, __shfl_xor(mx, 16));
        mx = fmaxf(mx, __shfl_xor(mx, 32));
        float e0 = __expf(sv[0] - mx), e1 = __expf(sv[1] - mx);
        float e2 = __expf(sv[2] - mx), e3 = __expf(sv[3] - mx);
        float sm = (e0 + e1) + (e2 + e3);
        sm += __shfl_xor(sm, 16);
        sm += __shfl_xor(sm, 32);
        const float inv = 1.0f / sm;
        // pack P row-chunk (k=4q..4q+3 of row i=l15) as 2 bf16-pairs, then
        // gather A-frag pf[j]=P[l15][k0+j] via 4 shfl (sources: same l15,
        // quads k0/4 and k0/4+1). Quads 2,3 cover k=16..31 -> all zeros.
        const unsigned p01 = pk2(e0*inv, e1*inv);
        const unsigned p23 = pk2(e2*inv, e3*inv);
        const int srcA = quad*32 + l15;     // valid for quad 0,1; 2,3 zeroed
        unsigned g0 = (unsigned)__shfl((int)p01, srcA);
        unsigned g1 = (unsigned)__shfl((int)p23, srcA);
        unsigned g2 = (unsigned)__shfl((int)p01, srcA + 16);
        unsigned g3 = (unsigned)__shfl((int)p23, srcA + 16);
        if (quad >= 2) { g0 = 0u; g1 = 0u; g2 = 0u; g3 = 0u; }
        bf16x8 pf;
        { unsigned gg[4] = {g0, g1, g2, g3}; __builtin_memcpy(&pf, gg, 16); }
        const short* vbase = vt + (w*4 + hh)*DHEAD*VTP;
#pragma unroll
        for (int t = 0; t < 2; ++t) {
          const bf16x8 vf = *(const bf16x8*)&vbase[(t*16 + l15)*VTP + k0];
          f32x4 oacc = {0.f,0.f,0.f,0.f};
          oacc = __builtin_amdgcn_mfma_f32_16x16x32_bf16(pf, vf, oacc, 0,0,0);
          const int d = t*16 + l15;
          if (d < DHEAD) {
#pragma unroll
            for (int r = 0; r < 4; ++r) {
              const int i2 = quad*4 + r;
              if (i2 < 10)
                xo[(w*10 + i2)*XPITCH + hh*DHEAD + d] = f2bf(oacc[r]);
            }
          }
        }
      }
      __syncthreads();

      // ---- output projection: wave = N-tile (waves 0..5) ----
      if (wave < 6) {
        for (int m = 0; m < 3; ++m) {
          const bf16x8 a0 = *(const bf16x8*)&xo[(m*16 + l15)*XPITCH +  0 + k0];
          const bf16x8 a1 = *(const bf16x8*)&xo[(m*16 + l15)*XPITCH + 32 + k0];
          const bf16x8 a2 = *(const bf16x8*)&xo[(m*16 + l15)*XPITCH + 64 + k0];
          f32x4 acc = {0.f,0.f,0.f,0.f};
          acc = __builtin_amdgcn_mfma_f32_16x16x32_bf16(a0, bwo[0], acc, 0,0,0);
          acc = __builtin_amdgcn_mfma_f32_16x16x32_bf16(a1, bwo[1], acc, 0,0,0);
          acc = __builtin_amdgcn_mfma_f32_16x16x32_bf16(a2, bwo[2], acc, 0,0,0);
          const int col = wave*16 + l15;
#pragma unroll
          for (int r = 0; r < 4; ++r) {
            const int R = m*16 + quad*4 + r;
            if (R < ROWS)
              out[(rowbase + R)*EDIM + col] = acc[r] + bo_val;
          }
        }
      }
      __syncthreads();
    }
}

extern "C" void kernel_launch(void* const* d_in, const int* in_sizes, int n_in,
                              void* d_out, int out_size, void* d_ws, size_t ws_size,
                              hipStream_t stream) {
    const float* X    = (const float*)d_in[0];
    const float* Wqkv = (const float*)d_in[1];
    const float* bqkv = (const float*)d_in[2];
    const float* Wo   = (const float*)d_in[3];
    const float* bo   = (const float*)d_in[4];
    const float* pos  = (const float*)d_in[5];
    float* out = (float*)d_out;

    (void)hipFuncSetAttribute((const void*)swin_msa_fused,
                              hipFuncAttributeMaxDynamicSharedMemorySize,
                              SMEM_BYTES);
    swin_msa_fused<<<dim3(NBLOCKS), dim3(NTHREADS), SMEM_BYTES, stream>>>(
        X, Wqkv, bqkv, Wo, bo, pos, out);
}